// Round 4
// baseline (262.791 us; speedup 1.0000x reference)
//
#include <hip/hip_runtime.h>

// Positional encoding off-grid: out[c, i] layout (256, num), row-major, fp32.
//   c in [0,128):   c=2k -> sin(y_i * f_k), c=2k+1 -> cos(y_i * f_k)
//   c in [128,256): c-128=2k -> sin(x_i * f_k), else cos(x_i * f_k)
// Write-BW bound: 268 MB out, ~2 MB in. Kernel floor ~42 us @ 6.4 TB/s.
// NOTE (R1): bench dur_us includes ~205 us of harness re-poison fills
// (1 GiB d_ws + 268 MB d_out at ~6.5 TB/s, seen in rocprof as
// fillBufferAligned); kernel-attributable time is dur_us - ~205.

typedef float v4f __attribute__((ext_vector_type(4)));  // native vector: NT-store OK

__global__ __launch_bounds__(256) void pe_offgrid_kernel(
    const float* __restrict__ YX,        // (2, num)
    const float* __restrict__ inv_freq,  // (64,)
    float* __restrict__ out,             // (256, num)
    int num)
{
    __shared__ float fshared[64];
    if (threadIdx.x < 64) fshared[threadIdx.x] = inv_freq[threadIdx.x];
    __syncthreads();

    const unsigned i4 = blockIdx.x * blockDim.x + threadIdx.x;  // float4 chunk over i
    if (4u * i4 >= (unsigned)num) return;

    const int slice = blockIdx.y;        // 0..7, each covers 16 of the 128 (coord,k) pairs
    const int kk0   = slice * 16;
    const bool isY  = (kk0 < 64);

    // coord values for the 4 consecutive i's this thread owns
    const v4f c4 = ((const v4f*)(YX + (isY ? 0 : num)))[i4];
    const float a0 = c4.x, a1 = c4.y, a2 = c4.z, a3 = c4.w;
    const unsigned col = 4u * i4;                 // column index (floats)
    const unsigned rowBase = isY ? 0u : 128u;     // first output row of this half

#pragma unroll
    for (int j = 0; j < 16; ++j) {
        const int k  = (kk0 + j) & 63;           // frequency index
        const float fr = fshared[k];

        float s0, s1, s2, s3, cc0, cc1, cc2, cc3;   // scalars: &elem of ext_vector illegal
        __sincosf(a0 * fr, &s0, &cc0);
        __sincosf(a1 * fr, &s1, &cc1);
        __sincosf(a2 * fr, &s2, &cc2);
        __sincosf(a3 * fr, &s3, &cc3);
        const v4f s = {s0, s1, s2, s3};
        const v4f c = {cc0, cc1, cc2, cc3};

        // 32-bit offsets: total extent 256*262144*4 B = 2^28, fits uint32.
        const unsigned rowS = (rowBase + 2u * (unsigned)k) * (unsigned)num + col;
        __builtin_nontemporal_store(s, (v4f*)(out + rowS));        // sin row
        __builtin_nontemporal_store(c, (v4f*)(out + rowS + num));  // cos row
    }
}

extern "C" void kernel_launch(void* const* d_in, const int* in_sizes, int n_in,
                              void* d_out, int out_size, void* d_ws, size_t ws_size,
                              hipStream_t stream) {
    const float* YX       = (const float*)d_in[0];
    const float* inv_freq = (const float*)d_in[1];
    float* out            = (float*)d_out;

    const int num = in_sizes[0] / 2;          // 262144
    const int i4_total = (num + 3) / 4;       // 65536
    dim3 block(256);
    dim3 grid((i4_total + block.x - 1) / block.x, 8);
    pe_offgrid_kernel<<<grid, block, 0, stream>>>(YX, inv_freq, out, num);
}